// Round 1
// baseline (457.530 us; speedup 1.0000x reference)
//
#include <hip/hip_runtime.h>

// UnPooling: x[32,112,112,64] f32 -> out[32,224,224,64] f32,
// out[:, ::2, ::2, :] = x, everything else zero.
// Output-driven, one float4 (4 channels) per thread, fully coalesced stores.
//
// Grid: (14, 224, 32): blockIdx.x*256+tid = float4 index j within one output
// row (224 px * 16 float4/px = 3584 = 14*256); blockIdx.y = output row oh;
// blockIdx.z = batch b. No integer division anywhere.

__global__ __launch_bounds__(256) void unpool_kernel(
    const float4* __restrict__ x, float4* __restrict__ out) {
    const int j  = blockIdx.x * 256 + threadIdx.x; // float4 idx within row [0,3584)
    const int oh = blockIdx.y;                     // [0,224)
    const int b  = blockIdx.z;                     // [0,32)
    const int c4 = j & 15;                         // float4 idx within pixel
    const int ow = j >> 4;                         // output col [0,224)

    float4 v = make_float4(0.f, 0.f, 0.f, 0.f);
    if (((oh | ow) & 1) == 0) {
        // source pixel (b, oh/2, ow/2), channel group c4
        v = x[((b * 112 + (oh >> 1)) * 112 + (ow >> 1)) * 16 + c4];
    }
    out[(b * 224 + oh) * 3584 + j] = v;
}

extern "C" void kernel_launch(void* const* d_in, const int* in_sizes, int n_in,
                              void* d_out, int out_size, void* d_ws, size_t ws_size,
                              hipStream_t stream) {
    const float4* x = (const float4*)d_in[0];
    float4* out = (float4*)d_out;
    dim3 grid(14, 224, 32);
    dim3 block(256);
    unpool_kernel<<<grid, block, 0, stream>>>(x, out);
}

// Round 3
// 452.253 us; speedup vs baseline: 1.0117x; 1.0117x over previous
//
#include <hip/hip_runtime.h>

// UnPooling: x[32,112,112,64] f32 -> out[32,224,224,64] f32,
// out[:, ::2, ::2, :] = x, rest zero.
//
// Each thread: 2 column chunks (j, j+256) x 2 output rows (2h data, 2h+1 zero)
// = 4 independent float4 stores + up to 2 loads. Zero stores issued first so
// they don't wait on the loads. j and j+256 have the same pixel parity
// (columns differ by 16), so one branch covers both chunks.
// All stores fully coalesced (adjacent lanes -> adjacent 16B).
//
// Nontemporal builtins need native clang vectors, not HIP_vector_type.
typedef float f4 __attribute__((ext_vector_type(4)));

__global__ __launch_bounds__(256) void unpool_kernel(
    const f4* __restrict__ x, f4* __restrict__ out) {
    const int tid = threadIdx.x;
    const int j0  = blockIdx.x * 512 + tid;  // float4 col idx [0,3584)
    const int j1  = j0 + 256;
    const int h   = blockIdx.y;              // input row [0,112)
    const int b   = blockIdx.z;

    const int c4_0 = j0 & 15, ow0 = j0 >> 4; // ow0 in [0,224)
    const int c4_1 = j1 & 15, ow1 = j1 >> 4;

    const f4 z = (f4){0.f, 0.f, 0.f, 0.f};

    f4* orow_e = out + (size_t)(b * 224 + 2 * h) * 3584; // even out row
    f4* orow_o = orow_e + 3584;                          // odd out row

    // Odd row: pure zeros, independent of any load — issue first.
    __builtin_nontemporal_store(z, &orow_o[j0]);
    __builtin_nontemporal_store(z, &orow_o[j1]);

    f4 v0 = z, v1 = z;
    if ((ow0 & 1) == 0) { // same parity for ow1
        const f4* xrow = x + (size_t)(b * 112 + h) * (112 * 16);
        v0 = __builtin_nontemporal_load(&xrow[(ow0 >> 1) * 16 + c4_0]);
        v1 = __builtin_nontemporal_load(&xrow[(ow1 >> 1) * 16 + c4_1]);
    }
    __builtin_nontemporal_store(v0, &orow_e[j0]);
    __builtin_nontemporal_store(v1, &orow_e[j1]);
}

extern "C" void kernel_launch(void* const* d_in, const int* in_sizes, int n_in,
                              void* d_out, int out_size, void* d_ws, size_t ws_size,
                              hipStream_t stream) {
    const f4* x = (const f4*)d_in[0];
    f4* out = (f4*)d_out;
    dim3 grid(7, 112, 32);
    dim3 block(256);
    unpool_kernel<<<grid, block, 0, stream>>>(x, out);
}